// Round 14
// baseline (429.742 us; speedup 1.0000x reference)
//
#include <hip/hip_runtime.h>

#define NN 50000
#define EE 800000
#define DD 128
#define RR 8
#define SLOTS 9        // 8 rels + root/self
#define KSTACK 1152    // SLOTS*DD
#define NR2 (NN * RR)  // 400000
#define GRPB 16        // rows per gemmH block
#define STROW 304      // staging row stride bytes (144 bf16 = 288B + 16 pad)
#define STW (GRPB * STROW)   // 4864 B per-wave staging

typedef __attribute__((ext_vector_type(8))) short bf16x8;
typedef __attribute__((ext_vector_type(4))) float f32x4;

__device__ inline float bf2f(ushort u) {
    union { uint i; float f; } v; v.i = ((uint)u) << 16; return v.f;
}
__device__ inline ushort f2bf(float f) {
    uint b = __float_as_uint(f);
    uint r = (b + 0x7fffu + ((b >> 16) & 1u)) >> 16;
    return (ushort)r;
}

// Build BT[c][i] (c = s*128+o, i = 0..127) for both layers.
__global__ void __launch_bounds__(256) k_build_w4(
        const float* __restrict__ b0, const float* __restrict__ c0,
        const float* __restrict__ r0, const float* __restrict__ b1,
        const float* __restrict__ c1, const float* __restrict__ r1,
        ushort* __restrict__ w0, ushort* __restrict__ w1) {
    __shared__ float tile[32][132];
    const float* basis = blockIdx.y ? b1 : b0;
    const float* comp  = blockIdx.y ? c1 : c0;
    const float* root  = blockIdx.y ? r1 : r0;
    ushort* wT         = blockIdx.y ? w1 : w0;
    int tid = threadIdx.x;
    int k0 = blockIdx.x * 32;
    #pragma unroll
    for (int it = 0; it < 16; ++it) {
        int idx = it * 256 + tid;
        int kk = idx >> 7, o = idx & 127;
        int k = k0 + kk;
        float val;
        if (k < RR * DD) {
            int r = k >> 7, i = k & 127;
            float s = 0.f;
            #pragma unroll
            for (int b = 0; b < 8; ++b) s += comp[r * 8 + b] * basis[(b * 128 + i) * 128 + o];
            val = s;
        } else {
            val = root[(k - RR * DD) * 128 + o];
        }
        tile[kk][o] = val;
    }
    __syncthreads();
    int o = tid >> 1, half = tid & 1;
    int s = k0 >> 7, i0 = k0 & 127;
    ushort* wp = wT + ((size_t)(s * 128 + o)) * 128 + i0 + half * 16;
    #pragma unroll
    for (int j = 0; j < 8; ++j) {
        float lo = tile[half * 16 + 2 * j][o];
        float hi = tile[half * 16 + 2 * j + 1][o];
        uint pk;
        asm("v_cvt_pk_bf16_f32 %0, %1, %2" : "=v"(pk) : "v"(lo), "v"(hi));
        *(uint*)(wp + 2 * j) = pk;
    }
}

__global__ void k_hist(const int* __restrict__ ei, const int* __restrict__ et,
                       int* __restrict__ deg_dr, int* __restrict__ row_cnt) {
    int e = blockIdx.x * 256 + threadIdx.x;
    if (e < EE) {
        int d = ei[EE + e], t = et[e];
        atomicAdd(&deg_dr[d * RR + t], 1);
        atomicAdd(&row_cnt[d], 1);
    }
}

__global__ void k_scan1(const int* __restrict__ cnt, int* __restrict__ bsum, int n) {
    __shared__ int s[256];
    int t = threadIdx.x;
    int i = blockIdx.x * 256 + t;
    s[t] = (i < n) ? cnt[i] : 0;
    __syncthreads();
    for (int o = 128; o > 0; o >>= 1) {
        if (t < o) s[t] += s[t + o];
        __syncthreads();
    }
    if (t == 0) bsum[blockIdx.x] = s[0];
}

__global__ void k_scan2(int* __restrict__ bsum, int nb) {
    __shared__ int s[256];
    int t = threadIdx.x;
    int v = (t < nb) ? bsum[t] : 0;
    s[t] = v;
    __syncthreads();
    for (int o = 1; o < 256; o <<= 1) {
        int u = (t >= o) ? s[t - o] : 0;
        __syncthreads();
        s[t] += u;
        __syncthreads();
    }
    if (t < nb) bsum[t] = s[t] - v;   // exclusive
}

__global__ void k_scan3(const int* __restrict__ cnt, const int* __restrict__ boff,
                        int* __restrict__ ptr, int n) {
    __shared__ int s[256];
    int t = threadIdx.x;
    int i = blockIdx.x * 256 + t;
    int v = (i < n) ? cnt[i] : 0;
    s[t] = v;
    __syncthreads();
    for (int o = 1; o < 256; o <<= 1) {
        int u = (t >= o) ? s[t - o] : 0;
        __syncthreads();
        s[t] += u;
        __syncthreads();
    }
    if (i < n) ptr[i + 1] = boff[blockIdx.x] + s[t];
    if (i == 0) ptr[0] = 0;
}

// Per edge at dst-sorted position: {key = src*9+rel, w = 1/deg(dst,rel)}.
__global__ void k_scatter(const int* __restrict__ ei, const int* __restrict__ et,
                          const int* __restrict__ row_ptr, const int* __restrict__ deg_dr,
                          int* __restrict__ cursor, int2* __restrict__ ekw) {
    int e = blockIdx.x * 256 + threadIdx.x;
    if (e < EE) {
        int s = ei[e], d = ei[EE + e], t = et[e];
        int p = row_ptr[d] + atomicAdd(&cursor[d], 1);
        int2 pk;
        pk.x = s * SLOTS + t;
        pk.y = __float_as_int(1.f / (float)deg_dr[d * RR + t]);
        ekw[p] = pk;
    }
}

// Dense transform, occupancy-optimized: block = 256 threads (4 waves),
// 16 rows x 576 cols (grid.y = 2 col-halves). Wave = 16 rows x 144 cols
// (9 frags, acc 36 regs). LDS = max(A-tile 4KB, 4x4864B staging) = 19.5KB
// -> 6-8 blocks/CU (24-32 waves) to feed the write path.
// Epilogue: stage wave tile in padded LDS, copy out as 288 x 16B chunks.
__global__ void __launch_bounds__(256, 4) k_gemmH4(
        const float* __restrict__ Af32, const ushort* __restrict__ Abf,
        const ushort* __restrict__ BT, ushort* __restrict__ H) {
    __shared__ char lds[4 * STW];   // 19,456 B; first 4KB doubles as A-tile
    char* atb = lds;
    int tid = threadIdx.x, wid = tid >> 6, lane = tid & 63;
    int blockrow = blockIdx.x * GRPB;          // grid exact: 3125*16 == NN
    int colbase = blockIdx.y * 576 + wid * 144;

    // stage A-tile (16 rows x 128): thread t -> row t>>4, 16B segment t&15
    {
        int row = tid >> 4, seg = tid & 15;
        int gr = blockrow + row;
        uint4 pk;
        if (Af32) {
            const float4* sp = (const float4*)(Af32 + (size_t)gr * DD + seg * 8);
            float4 v0 = sp[0], v1 = sp[1];
            asm("v_cvt_pk_bf16_f32 %0, %1, %2" : "=v"(pk.x) : "v"(v0.x), "v"(v0.y));
            asm("v_cvt_pk_bf16_f32 %0, %1, %2" : "=v"(pk.y) : "v"(v0.z), "v"(v0.w));
            asm("v_cvt_pk_bf16_f32 %0, %1, %2" : "=v"(pk.z) : "v"(v1.x), "v"(v1.y));
            asm("v_cvt_pk_bf16_f32 %0, %1, %2" : "=v"(pk.w) : "v"(v1.z), "v"(v1.w));
        } else {
            pk = *(const uint4*)(Abf + (size_t)gr * DD + seg * 8);
        }
        uint off = (uint)(row * 256) + (((uint)seg * 16) ^ ((uint)(row & 7) << 4));
        *(uint4*)(atb + off) = pk;
    }
    __syncthreads();

    int rlo = lane & 15, q = lane >> 4;
    f32x4 acc[9];
    #pragma unroll
    for (int c = 0; c < 9; ++c) acc[c] = (f32x4){0.f, 0.f, 0.f, 0.f};

    const ushort* bp = BT + (size_t)(colbase + rlo) * DD + q * 8;
    uint x7 = (uint)(rlo & 7) << 4;
    #pragma unroll
    for (int kk = 0; kk < 4; ++kk) {
        uint loff = ((uint)(kk * 64 + q * 16)) ^ x7;
        bf16x8 a = *(const bf16x8*)(atb + rlo * 256 + loff);
        #pragma unroll
        for (int c = 0; c < 9; ++c) {
            bf16x8 b = *(const bf16x8*)(bp + (size_t)c * 16 * DD + kk * 32);
            acc[c] = __builtin_amdgcn_mfma_f32_16x16x32_bf16(a, b, acc[c], 0, 0, 0);
        }
    }
    __syncthreads();   // retire A-tile reads before LDS reuse as staging

    // stage wave's 16x144 bf16 tile (row stride 304B; 2-way-max bank aliasing)
    char* stb = lds + wid * STW;
    #pragma unroll
    for (int c = 0; c < 9; ++c) {
        #pragma unroll
        for (int rg = 0; rg < 4; ++rg) {
            int r = q * 4 + rg;
            *(ushort*)(stb + r * STROW + (c * 16 + rlo) * 2) = f2bf(acc[c][rg]);
        }
    }
    // coalesced copy-out: 288 chunks of 16B per wave; r = ci/18 via magic
    #pragma unroll
    for (int k = 0; k < 5; ++k) {
        int ci = k * 64 + lane;
        if (ci < 288) {
            int r = (int)(((uint)ci * 58255u) >> 20);
            int j = ci - r * 18;
            uint4 v = *(const uint4*)(stb + r * STROW + j * 16);
            *(uint4*)(H + (size_t)(blockrow + r) * KSTACK + colbase + j * 8) = v;
        }
    }
}

// Gather-aggregate: out[n] = bias + H[n*9+8] + sum_e w_e * H[key_e].
// One wave per dst row; flat edge loop, unroll 4. (Proven.)
__global__ void __launch_bounds__(256) k_agg2(const ushort* __restrict__ H,
                                              const int* __restrict__ row_ptr,
                                              const int2* __restrict__ ekw,
                                              const float* __restrict__ bias,
                                              ushort* __restrict__ hout,
                                              float* __restrict__ fout) {
    int wid = threadIdx.x >> 6, lane = threadIdx.x & 63;
    int n = blockIdx.x * 4 + wid;   // grid exact: 12500*4 == NN
    int l2 = lane << 1;
    uint su = *(const uint*)(H + ((size_t)n * SLOTS + RR) * DD + l2);
    float a0 = bf2f((ushort)(su & 0xffffu));
    float a1 = bf2f((ushort)(su >> 16));
    int p = row_ptr[n], p1 = row_ptr[n + 1];
    for (; p + 4 <= p1; p += 4) {
        int2 e0 = ekw[p], e1 = ekw[p + 1], e2 = ekw[p + 2], e3 = ekw[p + 3];
        uint u0 = *(const uint*)(H + (size_t)e0.x * DD + l2);
        uint u1 = *(const uint*)(H + (size_t)e1.x * DD + l2);
        uint u2 = *(const uint*)(H + (size_t)e2.x * DD + l2);
        uint u3 = *(const uint*)(H + (size_t)e3.x * DD + l2);
        float w0 = __int_as_float(e0.y), w1 = __int_as_float(e1.y);
        float w2 = __int_as_float(e2.y), w3 = __int_as_float(e3.y);
        a0 += w0 * bf2f((ushort)(u0 & 0xffffu)) + w1 * bf2f((ushort)(u1 & 0xffffu))
            + w2 * bf2f((ushort)(u2 & 0xffffu)) + w3 * bf2f((ushort)(u3 & 0xffffu));
        a1 += w0 * bf2f((ushort)(u0 >> 16)) + w1 * bf2f((ushort)(u1 >> 16))
            + w2 * bf2f((ushort)(u2 >> 16)) + w3 * bf2f((ushort)(u3 >> 16));
    }
    for (; p < p1; ++p) {
        int2 e = ekw[p];
        uint u = *(const uint*)(H + (size_t)e.x * DD + l2);
        float w = __int_as_float(e.y);
        a0 += w * bf2f((ushort)(u & 0xffffu));
        a1 += w * bf2f((ushort)(u >> 16));
    }
    a0 += bias[l2];
    a1 += bias[l2 + 1];
    if (hout) {
        a0 = fmaxf(a0, 0.f);
        a1 = fmaxf(a1, 0.f);
        *(uint*)(hout + (size_t)n * DD + l2) = (uint)f2bf(a0) | ((uint)f2bf(a1) << 16);
    } else {
        float2 v; v.x = a0; v.y = a1;
        *(float2*)(fout + (size_t)n * DD + l2) = v;
    }
}

extern "C" void kernel_launch(void* const* d_in, const int* in_sizes, int n_in,
                              void* d_out, int out_size, void* d_ws, size_t ws_size,
                              hipStream_t stream) {
    const float* x      = (const float*)d_in[0];
    const int*   ei     = (const int*)d_in[1];
    const int*   et     = (const int*)d_in[2];
    const float* basis0 = (const float*)d_in[3];
    const float* comp0  = (const float*)d_in[4];
    const float* root0  = (const float*)d_in[5];
    const float* bias0  = (const float*)d_in[6];
    const float* basis1 = (const float*)d_in[7];
    const float* comp1  = (const float*)d_in[8];
    const float* root1  = (const float*)d_in[9];
    const float* bias1  = (const float*)d_in[10];
    float* out = (float*)d_out;

    char* ws = (char*)d_ws;
    size_t off = 0;
    auto alloc = [&](size_t bytes) -> void* {
        void* p = ws + off;
        off += (bytes + 255) & ~(size_t)255;
        return p;
    };
    int*    deg_dr  = (int*)alloc((size_t)NR2 * 4);
    int*    row_cnt = (int*)alloc((size_t)NN * 4);
    int*    cursor  = (int*)alloc((size_t)NN * 4);
    size_t zero_bytes = off;
    int*    row_ptr = (int*)alloc((size_t)(NN + 1) * 4);
    int*    bsum    = (int*)alloc(256 * 4);
    int2*   ekw     = (int2*)alloc((size_t)EE * 8);
    ushort* BT0     = (ushort*)alloc((size_t)KSTACK * DD * 2);
    ushort* BT1     = (ushort*)alloc((size_t)KSTACK * DD * 2);
    ushort* h       = (ushort*)alloc((size_t)NN * DD * 2);
    ushort* H       = (ushort*)alloc((size_t)NN * KSTACK * 2);
    if (off > ws_size) return;

    hipMemsetAsync(d_ws, 0, zero_bytes, stream);

    dim3 wgrid(KSTACK / 32, 2);   // 36 x 2
    k_build_w4<<<wgrid, 256, 0, stream>>>(basis0, comp0, root0, basis1, comp1, root1, BT0, BT1);
    k_hist<<<3125, 256, 0, stream>>>(ei, et, deg_dr, row_cnt);
    k_scan1<<<196, 256, 0, stream>>>(row_cnt, bsum, NN);
    k_scan2<<<1, 256, 0, stream>>>(bsum, 196);
    k_scan3<<<196, 256, 0, stream>>>(row_cnt, bsum, row_ptr, NN);
    k_scatter<<<3125, 256, 0, stream>>>(ei, et, row_ptr, deg_dr, cursor, ekw);

    dim3 ggrid(NN / GRPB, 2);   // 3125 x 2, exact
    // Layer 0
    k_gemmH4<<<ggrid, 256, 0, stream>>>(x, nullptr, BT0, H);
    k_agg2<<<12500, 256, 0, stream>>>(H, row_ptr, ekw, bias0, h, nullptr);
    // Layer 1
    k_gemmH4<<<ggrid, 256, 0, stream>>>(nullptr, h, BT1, H);
    k_agg2<<<12500, 256, 0, stream>>>(H, row_ptr, ekw, bias1, nullptr, out);
}